// Round 5
// baseline (223.755 us; speedup 1.0000x reference)
//
#include <hip/hip_runtime.h>

#define NCOMM 512
#define DIM   128
#define ALPHA 0.25f
#define PEPS  1e-6f
#define BIGF  1e30f
#define TILE_C 32

typedef __attribute__((ext_vector_type(8))) short bf16x8;
typedef __attribute__((ext_vector_type(4))) float f32x4;

__device__ __forceinline__ unsigned short bf16_rn(float v) {
    unsigned u = __float_as_uint(v);
    u += 0x7FFFu + ((u >> 16) & 1u);
    return (unsigned short)(u >> 16);
}
__device__ __forceinline__ float bf16_f(unsigned short h) {
    return __uint_as_float((unsigned)h << 16);
}

#define GLOAD_LDS16(g, l) __builtin_amdgcn_global_load_lds( \
    (const __attribute__((address_space(1))) void*)(g), \
    (__attribute__((address_space(3))) void*)(l), 16, 0, 0)

// ---------------- small prep kernels ----------------

__global__ void k_inv(const int* __restrict__ cbl, int* __restrict__ inv, int N) {
    int i = blockIdx.x * 256 + threadIdx.x;
    if (i < N) inv[cbl[i]] = i;   // perm is a permutation: direct store == scatter-add on zeros
}

__global__ void k_comm(const int* __restrict__ cbl, const int* __restrict__ inv,
                       int* __restrict__ comm, int* __restrict__ idx0,
                       int* __restrict__ counts, int N) {
    __shared__ int h[NCOMM];
    int t = threadIdx.x;
    h[t] = 0; h[t + 256] = 0;
    __syncthreads();
    int j = blockIdx.x * 256 + t;
    if (j < N) {
        int ij = inv[j];
        int c  = cbl[N + ij];
        comm[j] = c;
        idx0[j] = cbl[ij];
        atomicAdd(&h[c], 1);
    }
    __syncthreads();
    int v = h[t];        if (v) atomicAdd(&counts[t], v);
    v = h[t + 256];      if (v) atomicAdd(&counts[t + 256], v);
}

__global__ void k_scan(const int* __restrict__ counts, int* __restrict__ offsets,
                       int* __restrict__ cursor, float* __restrict__ countf) {
    __shared__ int sc[NCOMM];
    int t = threadIdx.x;
    int v0 = counts[t];
    sc[t] = v0;
    __syncthreads();
    for (int off = 1; off < NCOMM; off <<= 1) {
        int v = (t >= off) ? sc[t - off] : 0;
        __syncthreads();
        sc[t] += v;
        __syncthreads();
    }
    int excl = sc[t] - v0;
    offsets[t] = excl;
    cursor[t]  = excl;
    countf[t]  = (float)v0;
}

// 1024 elements per block: LDS histogram + one range-reservation atomic per present comm
__global__ void k_sort(const int* __restrict__ comm, int* __restrict__ cursor,
                       int* __restrict__ sorted, int N) {
    __shared__ int h[NCOMM], hb[NCOMM];
    int t = threadIdx.x;
    h[t] = 0; h[t + 256] = 0;
    __syncthreads();
    int j0 = blockIdx.x * 1024 + t;
    int cs[4];
    #pragma unroll
    for (int q = 0; q < 4; ++q) {
        int j = j0 + q * 256;
        cs[q] = (j < N) ? comm[j] : -1;
        if (cs[q] >= 0) atomicAdd(&h[cs[q]], 1);
    }
    __syncthreads();
    int v = h[t];        if (v) hb[t] = atomicAdd(&cursor[t], v);
    v = h[t + 256];      if (v) hb[t + 256] = atomicAdd(&cursor[t + 256], v);
    __syncthreads();
    #pragma unroll
    for (int q = 0; q < 4; ++q) {
        int j = j0 + q * 256;
        if (cs[q] >= 0) {
            int p = atomicAdd(&hb[cs[q]], 1);
            sorted[p] = j;
        }
    }
}

// ---------------- per-community stats: float4 gather, single pass ----------------
// var = (sumsq - cnt*m^2)/(cnt-1): benign cancellation (x~N(0,1), rel err ~1e-6)

__global__ void __launch_bounds__(256) k_stats(
        const float* __restrict__ NF, const int* __restrict__ idx0,
        const int* __restrict__ sorted, const int* __restrict__ offsets,
        const int* __restrict__ counts,
        float* __restrict__ comm_sum,
        unsigned short* __restrict__ CMh, unsigned short* __restrict__ CMl,
        float* __restrict__ c2, float* __restrict__ accum) {
    __shared__ int ridx[512];
    __shared__ float4 bufS[256], bufQ[256];
    int c = blockIdx.x, t = threadIdx.x;
    int d4 = t & 31, r = t >> 5;                 // 32 dim-quads x 8 row slots
    int cnt = counts[c], base = offsets[c];
    const float4* NF4 = (const float4*)NF;

    float4 s4 = make_float4(0.f, 0.f, 0.f, 0.f);
    float4 q4 = make_float4(0.f, 0.f, 0.f, 0.f);
    for (int chunk = 0; chunk < cnt; chunk += 512) {
        int m = min(cnt - chunk, 512);
        for (int i = t; i < m; i += 256) ridx[i] = idx0[sorted[base + chunk + i]];
        __syncthreads();
        for (int i = r; i < m; i += 8) {
            float4 v = NF4[(size_t)ridx[i] * 32 + d4];
            s4.x += v.x; s4.y += v.y; s4.z += v.z; s4.w += v.w;
            q4.x = fmaf(v.x, v.x, q4.x); q4.y = fmaf(v.y, v.y, q4.y);
            q4.z = fmaf(v.z, v.z, q4.z); q4.w = fmaf(v.w, v.w, q4.w);
        }
        __syncthreads();
    }
    bufS[t] = s4; bufQ[t] = q4;
    __syncthreads();
    if (t < 128) {
        float4 a = bufS[t], b = bufS[t + 128];
        a.x += b.x; a.y += b.y; a.z += b.z; a.w += b.w; bufS[t] = a;
        float4 e = bufQ[t], f = bufQ[t + 128];
        e.x += f.x; e.y += f.y; e.z += f.z; e.w += f.w; bufQ[t] = e;
    }
    __syncthreads();
    if (t < 64) {
        float4 a = bufS[t], b = bufS[t + 64];
        a.x += b.x; a.y += b.y; a.z += b.z; a.w += b.w; bufS[t] = a;
        float4 e = bufQ[t], f = bufQ[t + 64];
        e.x += f.x; e.y += f.y; e.z += f.z; e.w += f.w; bufQ[t] = e;
    }
    __syncthreads();
    if (t < 32) {
        float4 a = bufS[t], b = bufS[t + 32];
        a.x += b.x; a.y += b.y; a.z += b.z; a.w += b.w;
        float4 e = bufQ[t], f = bufQ[t + 32];
        e.x += f.x; e.y += f.y; e.z += f.z; e.w += f.w;
        float sarr[4] = {a.x, a.y, a.z, a.w};
        float qarr[4] = {e.x, e.y, e.z, e.w};
        float cf = (float)cnt;
        float mm = 0.f, ee = 0.f;
        #pragma unroll
        for (int k = 0; k < 4; ++k) {
            int d = t * 4 + k;
            float s = sarr[k];
            comm_sum[c * DIM + d] = s;
            float m = (cnt > 0) ? s / cf : 0.f;
            unsigned short h = bf16_rn(m);
            CMh[c * DIM + d] = h;
            CMl[c * DIM + d] = bf16_rn(m - bf16_f(h));
            float varn = fmaxf(fmaf(-cf * m, m, qarr[k]), 0.f);
            float stdv = sqrtf(varn / fmaxf(cf - 1.f, 1.f));
            float er = stdv - 1.f;
            mm = fmaf(m, m, mm);
            ee = fmaf(er, er, ee);
        }
        #pragma unroll
        for (int msk = 1; msk < 32; msk <<= 1) {
            mm += __shfl_xor(mm, msk);
            ee += __shfl_xor(ee, msk);
        }
        if (t == 0) {
            c2[c] = mm;
            atomicAdd(&accum[2], ee);
        }
    }
}

// ---------------- heavy kernel: MFMA distances, comm-split ----------------
// Grid = 2*RB blocks. Block (rb, ch) does 128 rows x 256 comms (half ch).
// 8 tiles of 32 comms, block-level LDS dbuf (32 KB), one barrier/tile (m97
// structure) -- at ~4 blocks/CU the barrier vmcnt drain is hidden by other
// blocks. Staging addresses precomputed, advanced by +8KB/tile.
// Partial sum/min per half -> global; ch==0 also computes pos/own (LOO).
// Triplet combine happens in k_trip.

__global__ void __launch_bounds__(256, 4) k_main(
        const float* __restrict__ NF,
        const unsigned short* __restrict__ CMh,
        const unsigned short* __restrict__ CMl,
        const float* __restrict__ comm_sum,
        const float* __restrict__ c2g,
        const float* __restrict__ countf,
        const int* __restrict__ comm,
        const int* __restrict__ idx0,
        float* __restrict__ sp, float* __restrict__ mp,
        float* __restrict__ pos_g, float* __restrict__ own_g,
        int N, int RB) {
    __shared__ unsigned short Bst[2][2][TILE_C * DIM];  // [buf][h/l] = 32 KB
    __shared__ float c2s[256];
    __shared__ int   comms[128];
    __shared__ float x2s[128];
    __shared__ float sums[128], mins[128];

    int tid = threadIdx.x;
    int bid = blockIdx.x;
    int ch  = (bid >= RB) ? 1 : 0;
    int rb  = bid - ch * RB;
    int w  = tid >> 6;    // wave 0..3
    int l  = tid & 63;
    int lr = l & 15;      // A row within 16-frag / B (comm) col
    int lk = l >> 4;      // k-group
    int n0 = rb * 128;
    int c0 = ch * 256;
    int NP = RB * 128;

    // precomputed staging pointers (advance +4096 ushorts = 8 KB per tile)
    const unsigned short* pH0; const unsigned short* pH1;
    const unsigned short* pL0; const unsigned short* pL1;
    {
        int r0 = tid >> 4;
        int s0 = (tid & 15) ^ (r0 & 15);
        pH0 = CMh + ((size_t)(c0 + r0) * 16 + s0) * 8;
        pH1 = CMh + ((size_t)(c0 + 16 + r0) * 16 + s0) * 8;
        pL0 = CMl + ((size_t)(c0 + r0) * 16 + s0) * 8;
        pL1 = CMl + ((size_t)(c0 + 16 + r0) * 16 + s0) * 8;
    }
    auto stage = [&](int b) {
        GLOAD_LDS16(pH0, &Bst[b][0][(size_t)(0 * 256 + w * 64) * 8]);
        GLOAD_LDS16(pH1, &Bst[b][0][(size_t)(1 * 256 + w * 64) * 8]);
        GLOAD_LDS16(pL0, &Bst[b][1][(size_t)(0 * 256 + w * 64) * 8]);
        GLOAD_LDS16(pL1, &Bst[b][1][(size_t)(1 * 256 + w * 64) * 8]);
        pH0 += 4096; pH1 += 4096; pL0 += 4096; pL1 += 4096;
    };
    stage(0);   // tile 0 lands during A conversion

    c2s[tid] = c2g[c0 + tid];
    if (tid < 128) {
        int gn = n0 + tid;
        comms[tid] = (gn < N) ? comm[gn] : -1;
    }

    // ---- A fragments (rows w*32 + mf*16 + lr) + exact fp32 x2
    bf16x8 ah[2][4], al[2][4];
    #pragma unroll
    for (int mf = 0; mf < 2; ++mf) {
        int n = n0 + w * 32 + mf * 16 + lr;
        const float4* src = (const float4*)NF + (size_t)n * 32 + lk * 2;
        float p2 = 0.f;
        #pragma unroll
        for (int ks = 0; ks < 4; ++ks) {
            float4 v0 = make_float4(0.f, 0.f, 0.f, 0.f), v1 = v0;
            if (n < N) { v0 = src[ks * 8]; v1 = src[ks * 8 + 1]; }
            float fr[8] = {v0.x, v0.y, v0.z, v0.w, v1.x, v1.y, v1.z, v1.w};
            bf16x8 hh, ll;
            #pragma unroll
            for (int t = 0; t < 8; ++t) {
                unsigned short h = bf16_rn(fr[t]);
                hh[t] = (short)h;
                ll[t] = (short)bf16_rn(fr[t] - bf16_f(h));
                p2 = fmaf(fr[t], fr[t], p2);
            }
            ah[mf][ks] = hh; al[mf][ks] = ll;
        }
        p2 += __shfl_xor(p2, 16);
        p2 += __shfl_xor(p2, 32);
        if (lk == 0) x2s[w * 32 + mf * 16 + lr] = p2;
    }
    __syncthreads();   // tile0 staged (vmcnt drained) + c2s/comms/x2s ready

    // per-lane per-row state (C layout: row = lk*4 + j, col = lr)
    float x2v[2][4], sumv[2][4], minv[2][4];
    int cnv[2][4];
    #pragma unroll
    for (int mf = 0; mf < 2; ++mf)
        #pragma unroll
        for (int j = 0; j < 4; ++j) {
            int idx = w * 32 + mf * 16 + lk * 4 + j;
            x2v[mf][j] = x2s[idx];
            cnv[mf][j] = comms[idx];
            sumv[mf][j] = 0.f; minv[mf][j] = BIGF;
        }

    int buf = 0;
    for (int tt = 0; tt < 8; ++tt) {
        if (tt < 7) stage(buf ^ 1);

        #pragma unroll
        for (int s = 0; s < 2; ++s) {
            int rbase = s * 16 + lr;
            const unsigned short* bhp = &Bst[buf][0][0];
            const unsigned short* blp = &Bst[buf][1][0];
            f32x4 ae0 = {0.f, 0.f, 0.f, 0.f}, ao0 = ae0, ae1 = ae0, ao1 = ae0;
            #pragma unroll
            for (int hf = 0; hf < 2; ++hf) {               // ks pair {2hf, 2hf+1}
                int ke = hf * 2, ko = hf * 2 + 1;
                int che = (ke * 4 + lk) ^ lr;
                int cho = (ko * 4 + lk) ^ lr;
                bf16x8 bhe = *(const bf16x8*)&bhp[(size_t)(rbase * 16 + che) * 8];
                bf16x8 bho = *(const bf16x8*)&bhp[(size_t)(rbase * 16 + cho) * 8];
                bf16x8 ble = *(const bf16x8*)&blp[(size_t)(rbase * 16 + che) * 8];
                bf16x8 blo = *(const bf16x8*)&blp[(size_t)(rbase * 16 + cho) * 8];
                ae0 = __builtin_amdgcn_mfma_f32_16x16x32_bf16(ah[0][ke], bhe, ae0, 0, 0, 0);
                ae1 = __builtin_amdgcn_mfma_f32_16x16x32_bf16(ah[1][ke], bhe, ae1, 0, 0, 0);
                ao0 = __builtin_amdgcn_mfma_f32_16x16x32_bf16(ah[0][ko], bho, ao0, 0, 0, 0);
                ao1 = __builtin_amdgcn_mfma_f32_16x16x32_bf16(ah[1][ko], bho, ao1, 0, 0, 0);
                ae0 = __builtin_amdgcn_mfma_f32_16x16x32_bf16(al[0][ke], bhe, ae0, 0, 0, 0);
                ae1 = __builtin_amdgcn_mfma_f32_16x16x32_bf16(al[1][ke], bhe, ae1, 0, 0, 0);
                ao0 = __builtin_amdgcn_mfma_f32_16x16x32_bf16(al[0][ko], bho, ao0, 0, 0, 0);
                ao1 = __builtin_amdgcn_mfma_f32_16x16x32_bf16(al[1][ko], bho, ao1, 0, 0, 0);
                ae0 = __builtin_amdgcn_mfma_f32_16x16x32_bf16(ah[0][ke], ble, ae0, 0, 0, 0);
                ae1 = __builtin_amdgcn_mfma_f32_16x16x32_bf16(ah[1][ke], ble, ae1, 0, 0, 0);
                ao0 = __builtin_amdgcn_mfma_f32_16x16x32_bf16(ah[0][ko], blo, ao0, 0, 0, 0);
                ao1 = __builtin_amdgcn_mfma_f32_16x16x32_bf16(ah[1][ko], blo, ao1, 0, 0, 0);
            }
            f32x4 acc0 = ae0 + ao0;
            f32x4 acc1 = ae1 + ao1;
            int ccl = tt * TILE_C + s * 16 + lr;       // local comm id in half
            int ccol = c0 + ccl;                        // global comm id
            float c2v = c2s[ccl];
            #pragma unroll
            for (int j = 0; j < 4; ++j) {
                float d2a = fmaf(-2.f, acc0[j], x2v[0][j] + c2v);
                float da  = __builtin_amdgcn_sqrtf(fmaxf(d2a, 0.f));
                sumv[0][j] += da;
                minv[0][j] = fminf(minv[0][j], (cnv[0][j] == ccol) ? BIGF : da);
                float d2b = fmaf(-2.f, acc1[j], x2v[1][j] + c2v);
                float db  = __builtin_amdgcn_sqrtf(fmaxf(d2b, 0.f));
                sumv[1][j] += db;
                minv[1][j] = fminf(minv[1][j], (cnv[1][j] == ccol) ? BIGF : db);
            }
        }
        __syncthreads();   // stage(tt+1) landed; all waves done reading buf
        buf ^= 1;
    }

    // reduce sum/min across the 16 lr lanes sharing each node row
    #pragma unroll
    for (int mf = 0; mf < 2; ++mf)
        #pragma unroll
        for (int j = 0; j < 4; ++j) {
            float sv = sumv[mf][j], mv = minv[mf][j];
            #pragma unroll
            for (int msk = 1; msk < 16; msk <<= 1) {
                sv += __shfl_xor(sv, msk);
                mv = fminf(mv, __shfl_xor(mv, msk));
            }
            if (lr == 0) {
                int idx = w * 32 + mf * 16 + lk * 4 + j;
                sums[idx] = sv; mins[idx] = mv;
            }
        }
    __syncthreads();

    // coalesced partial write
    if (tid < 128) {
        int n = n0 + tid;
        sp[(size_t)ch * NP + n] = sums[tid];
        mp[(size_t)ch * NP + n] = mins[tid];
    }

    // LOO positive distance + own distance (ch==0 blocks only; 2 thr/node)
    if (ch == 0) {
        int ln = tid >> 1, half = tid & 1;
        int n = n0 + ln;
        if (n < N) {
            int cnode = comms[ln];
            float cf  = countf[cnode];
            float cm1 = fmaxf(cf - 1.f, 1.f);
            float rs  = 1.f / cm1;
            bool single = (cf == 1.f);
            const float4* srow = (const float4*)(NF + (size_t)idx0[n] * DIM) + half * 16;
            const float4* csum = (const float4*)(comm_sum + (size_t)cnode * DIM) + half * 16;
            float q = 0.f, dot = 0.f;
            #pragma unroll
            for (int m = 0; m < 16; ++m) {
                float4 sv = srow[m];
                float4 cs = csum[m];
                float4 xm = single ? make_float4(0.f, 0.f, 0.f, 0.f) : sv;
                float lx = (cs.x - xm.x) * rs - sv.x + PEPS;
                float ly = (cs.y - xm.y) * rs - sv.y + PEPS;
                float lz = (cs.z - xm.z) * rs - sv.z + PEPS;
                float lw = (cs.w - xm.w) * rs - sv.w + PEPS;
                q = fmaf(lx, lx, fmaf(ly, ly, fmaf(lz, lz, fmaf(lw, lw, q))));
                dot = fmaf(sv.x, cs.x, fmaf(sv.y, cs.y, fmaf(sv.z, cs.z, fmaf(sv.w, cs.w, dot))));
            }
            q   += __shfl_xor(q, 1);
            dot += __shfl_xor(dot, 1);
            if (half == 0) {
                pos_g[n] = sqrtf(q);
                float ownd2 = x2s[ln] + c2g[cnode] - 2.f * (dot / cf);
                own_g[n] = sqrtf(fmaxf(ownd2, 0.f));
            }
        }
    }
}

// ---------------- triplet combine ----------------

__global__ void __launch_bounds__(256) k_trip(
        const float* __restrict__ sp, const float* __restrict__ mp,
        const float* __restrict__ pos_g, const float* __restrict__ own_g,
        float* __restrict__ accum, int N, int NP) {
    __shared__ float red[8];
    int i = blockIdx.x * 256 + threadIdx.x;
    float tm = 0.f, tn = 0.f;
    if (i < N) {
        float own = own_g[i];
        float sum = sp[i] + sp[(size_t)NP + i] - own;
        float mn  = fminf(mp[i], mp[(size_t)NP + i]);
        float pos = pos_g[i];
        tm = fmaxf(pos - sum * (1.f / (float)(NCOMM - 1)) + ALPHA, 0.f);
        tn = fmaxf(pos - mn + ALPHA, 0.f);
    }
    #pragma unroll
    for (int msk = 1; msk < 64; msk <<= 1) {
        tm += __shfl_xor(tm, msk);
        tn += __shfl_xor(tn, msk);
    }
    int wv = threadIdx.x >> 6;
    if ((threadIdx.x & 63) == 0) { red[wv * 2] = tm; red[wv * 2 + 1] = tn; }
    __syncthreads();
    if (threadIdx.x == 0) {
        atomicAdd(&accum[0], red[0] + red[2] + red[4] + red[6]);
        atomicAdd(&accum[1], red[1] + red[3] + red[5] + red[7]);
    }
}

__global__ void k_final(const float* __restrict__ accum, float* __restrict__ out, int N) {
    if (threadIdx.x == 0) {
        out[0] = accum[0] / (float)N;
        out[1] = accum[1] / (float)N;
        out[2] = accum[2] / (float)(NCOMM * DIM);
    }
}

// ---------------- launch ----------------

extern "C" void kernel_launch(void* const* d_in, const int* in_sizes, int n_in,
                              void* d_out, int out_size, void* d_ws, size_t ws_size,
                              hipStream_t stream) {
    const float* NF  = (const float*)d_in[0];
    const int*   CBL = (const int*)d_in[1];
    int N = in_sizes[1] / 2;
    if (N <= 0) return;
    int RB = (N + 127) / 128;
    int NP = RB * 128;

    char* ws = (char*)d_ws;
    float* accum   = (float*)ws;                    // 16 B
    int*   counts  = (int*)(ws + 16);               // 2048
    int*   cursor  = (int*)(ws + 16 + 2048);
    int*   offsets = (int*)(ws + 16 + 2 * 2048);
    float* countf  = (float*)(ws + 16 + 3 * 2048);
    float* c2      = (float*)(ws + 16 + 4 * 2048);
    char* p = ws + 16 + 5 * 2048;
    int* inv    = (int*)p; p += (size_t)N * 4;
    int* comm   = (int*)p; p += (size_t)N * 4;
    int* idx0   = (int*)p; p += (size_t)N * 4;
    int* sorted = (int*)p; p += (size_t)N * 4;
    float* comm_sum = (float*)p; p += (size_t)NCOMM * DIM * 4;
    unsigned short* CMh = (unsigned short*)p; p += (size_t)NCOMM * DIM * 2;
    unsigned short* CMl = (unsigned short*)p; p += (size_t)NCOMM * DIM * 2;
    float* sp    = (float*)p; p += (size_t)2 * NP * 4;
    float* mp    = (float*)p; p += (size_t)2 * NP * 4;
    float* pos_g = (float*)p; p += (size_t)NP * 4;
    float* own_g = (float*)p;

    hipMemsetAsync(d_ws, 0, 16 + 2048, stream);     // accum + counts

    int nb = (N + 255) / 256;
    k_inv <<<nb, 256, 0, stream>>>(CBL, inv, N);
    k_comm<<<nb, 256, 0, stream>>>(CBL, inv, comm, idx0, counts, N);
    k_scan<<<1, NCOMM, 0, stream>>>(counts, offsets, cursor, countf);
    int nb4 = (N + 1023) / 1024;
    k_sort<<<nb4, 256, 0, stream>>>(comm, cursor, sorted, N);
    k_stats<<<NCOMM, 256, 0, stream>>>(NF, idx0, sorted, offsets, counts,
                                       comm_sum, CMh, CMl, c2, accum);
    k_main<<<2 * RB, 256, 0, stream>>>(NF, CMh, CMl, comm_sum, c2, countf,
                                       comm, idx0, sp, mp, pos_g, own_g, N, RB);
    k_trip<<<(N + 255) / 256, 256, 0, stream>>>(sp, mp, pos_g, own_g, accum, N, NP);
    k_final<<<1, 64, 0, stream>>>(accum, (float*)d_out, N);
}

// Round 6
// 148.429 us; speedup vs baseline: 1.5075x; 1.5075x over previous
//
#include <hip/hip_runtime.h>

#define NCOMM 512
#define DIM   128
#define ALPHA 0.25f
#define PEPS  1e-6f
#define BIGF  1e30f
#define TILE_C 16
#define NT    (NCOMM / TILE_C)   // 32 tiles

typedef __attribute__((ext_vector_type(8))) short bf16x8;
typedef __attribute__((ext_vector_type(4))) float f32x4;

__device__ __forceinline__ unsigned short bf16_rn(float v) {
    unsigned u = __float_as_uint(v);
    u += 0x7FFFu + ((u >> 16) & 1u);
    return (unsigned short)(u >> 16);
}
__device__ __forceinline__ float bf16_f(unsigned short h) {
    return __uint_as_float((unsigned)h << 16);
}

#define GLOAD_LDS16(g, l) __builtin_amdgcn_global_load_lds( \
    (const __attribute__((address_space(1))) void*)(g), \
    (__attribute__((address_space(3))) void*)(l), 16, 0, 0)

// ---------------- small prep kernels ----------------

__global__ void k_inv(const int* __restrict__ cbl, int* __restrict__ inv, int N) {
    int i = blockIdx.x * 256 + threadIdx.x;
    if (i < N) inv[cbl[i]] = i;   // perm is a permutation: direct store == scatter-add on zeros
}

__global__ void k_comm(const int* __restrict__ cbl, const int* __restrict__ inv,
                       int* __restrict__ comm, int* __restrict__ idx0,
                       int* __restrict__ counts, int N) {
    __shared__ int h[NCOMM];
    int t = threadIdx.x;
    h[t] = 0; h[t + 256] = 0;
    __syncthreads();
    int j = blockIdx.x * 256 + t;
    if (j < N) {
        int ij = inv[j];
        int c  = cbl[N + ij];
        comm[j] = c;
        idx0[j] = cbl[ij];
        atomicAdd(&h[c], 1);
    }
    __syncthreads();
    int v = h[t];        if (v) atomicAdd(&counts[t], v);
    v = h[t + 256];      if (v) atomicAdd(&counts[t + 256], v);
}

__global__ void k_scan(const int* __restrict__ counts, int* __restrict__ offsets,
                       int* __restrict__ cursor, float* __restrict__ countf) {
    __shared__ int sc[NCOMM];
    int t = threadIdx.x;
    int v0 = counts[t];
    sc[t] = v0;
    __syncthreads();
    for (int off = 1; off < NCOMM; off <<= 1) {
        int v = (t >= off) ? sc[t - off] : 0;
        __syncthreads();
        sc[t] += v;
        __syncthreads();
    }
    int excl = sc[t] - v0;
    offsets[t] = excl;
    cursor[t]  = excl;
    countf[t]  = (float)v0;
}

// 1024 elements per block: LDS histogram + one range-reservation atomic per present comm
__global__ void k_sort(const int* __restrict__ comm, int* __restrict__ cursor,
                       int* __restrict__ sorted, int N) {
    __shared__ int h[NCOMM], hb[NCOMM];
    int t = threadIdx.x;
    h[t] = 0; h[t + 256] = 0;
    __syncthreads();
    int j0 = blockIdx.x * 1024 + t;
    int cs[4];
    #pragma unroll
    for (int q = 0; q < 4; ++q) {
        int j = j0 + q * 256;
        cs[q] = (j < N) ? comm[j] : -1;
        if (cs[q] >= 0) atomicAdd(&h[cs[q]], 1);
    }
    __syncthreads();
    int v = h[t];        if (v) hb[t] = atomicAdd(&cursor[t], v);
    v = h[t + 256];      if (v) hb[t + 256] = atomicAdd(&cursor[t + 256], v);
    __syncthreads();
    #pragma unroll
    for (int q = 0; q < 4; ++q) {
        int j = j0 + q * 256;
        if (cs[q] >= 0) {
            int p = atomicAdd(&hb[cs[q]], 1);
            sorted[p] = j;
        }
    }
}

// ---------------- per-community stats: float4 gather, single pass ----------------
// var = (sumsq - cnt*m^2)/(cnt-1): benign cancellation (x~N(0,1), rel err ~1e-6)

__global__ void __launch_bounds__(256) k_stats(
        const float* __restrict__ NF, const int* __restrict__ idx0,
        const int* __restrict__ sorted, const int* __restrict__ offsets,
        const int* __restrict__ counts,
        float* __restrict__ comm_sum,
        unsigned short* __restrict__ CMh, unsigned short* __restrict__ CMl,
        float* __restrict__ c2, float* __restrict__ accum) {
    __shared__ int ridx[512];
    __shared__ float4 bufS[256], bufQ[256];
    int c = blockIdx.x, t = threadIdx.x;
    int d4 = t & 31, r = t >> 5;                 // 32 dim-quads x 8 row slots
    int cnt = counts[c], base = offsets[c];
    const float4* NF4 = (const float4*)NF;

    float4 s4 = make_float4(0.f, 0.f, 0.f, 0.f);
    float4 q4 = make_float4(0.f, 0.f, 0.f, 0.f);
    for (int chunk = 0; chunk < cnt; chunk += 512) {
        int m = min(cnt - chunk, 512);
        for (int i = t; i < m; i += 256) ridx[i] = idx0[sorted[base + chunk + i]];
        __syncthreads();
        for (int i = r; i < m; i += 8) {
            float4 v = NF4[(size_t)ridx[i] * 32 + d4];
            s4.x += v.x; s4.y += v.y; s4.z += v.z; s4.w += v.w;
            q4.x = fmaf(v.x, v.x, q4.x); q4.y = fmaf(v.y, v.y, q4.y);
            q4.z = fmaf(v.z, v.z, q4.z); q4.w = fmaf(v.w, v.w, q4.w);
        }
        __syncthreads();
    }
    bufS[t] = s4; bufQ[t] = q4;
    __syncthreads();
    if (t < 128) {
        float4 a = bufS[t], b = bufS[t + 128];
        a.x += b.x; a.y += b.y; a.z += b.z; a.w += b.w; bufS[t] = a;
        float4 e = bufQ[t], f = bufQ[t + 128];
        e.x += f.x; e.y += f.y; e.z += f.z; e.w += f.w; bufQ[t] = e;
    }
    __syncthreads();
    if (t < 64) {
        float4 a = bufS[t], b = bufS[t + 64];
        a.x += b.x; a.y += b.y; a.z += b.z; a.w += b.w; bufS[t] = a;
        float4 e = bufQ[t], f = bufQ[t + 64];
        e.x += f.x; e.y += f.y; e.z += f.z; e.w += f.w; bufQ[t] = e;
    }
    __syncthreads();
    if (t < 32) {
        float4 a = bufS[t], b = bufS[t + 32];
        a.x += b.x; a.y += b.y; a.z += b.z; a.w += b.w;
        float4 e = bufQ[t], f = bufQ[t + 32];
        e.x += f.x; e.y += f.y; e.z += f.z; e.w += f.w;
        float sarr[4] = {a.x, a.y, a.z, a.w};
        float qarr[4] = {e.x, e.y, e.z, e.w};
        float cf = (float)cnt;
        float mm = 0.f, ee = 0.f;
        #pragma unroll
        for (int k = 0; k < 4; ++k) {
            int d = t * 4 + k;
            float s = sarr[k];
            comm_sum[c * DIM + d] = s;
            float m = (cnt > 0) ? s / cf : 0.f;
            unsigned short h = bf16_rn(m);
            CMh[c * DIM + d] = h;
            CMl[c * DIM + d] = bf16_rn(m - bf16_f(h));
            float varn = fmaxf(fmaf(-cf * m, m, qarr[k]), 0.f);
            float stdv = sqrtf(varn / fmaxf(cf - 1.f, 1.f));
            float er = stdv - 1.f;
            mm = fmaf(m, m, mm);
            ee = fmaf(er, er, ee);
        }
        #pragma unroll
        for (int msk = 1; msk < 32; msk <<= 1) {
            mm += __shfl_xor(mm, msk);
            ee += __shfl_xor(ee, msk);
        }
        if (t == 0) {
            c2[c] = mm;
            atomicAdd(&accum[2], ee);
        }
    }
}

// ---------------- heavy kernel: MFMA distances + triplet terms ----------------
// 256 threads (4 waves x 64 rows = 256 nodes/block), grid = ceil(N/256) = 391:
// all blocks co-resident (2/CU), single generation. B tiles WAVE-PRIVATE
// double-buffered LDS (TILE_C=16), counted s_waitcnt vmcnt(8), NO barrier in
// the K-loop. M=64/wave doubles MFMA per B ds_read vs round 4 (48 MFMA per
// 8 b-frag reads). acc is C-initialized with -x^2/2 (read from LDS per tile)
// so x2 needs no persistent registers. 4 acc chains interleaved at 4-inst
// spacing ~ MFMA dep latency.

__global__ void __launch_bounds__(256, 2) k_main(
        const float* __restrict__ NF,
        const unsigned short* __restrict__ CMh,
        const unsigned short* __restrict__ CMl,
        const float* __restrict__ comm_sum,
        const float* __restrict__ c2g,
        const float* __restrict__ countf,
        const int* __restrict__ comm,
        const int* __restrict__ idx0,
        float* __restrict__ accum, int N) {
    __shared__ unsigned short Bst[4][2][2][TILE_C * DIM];  // [wave][buf][h/l] = 64 KB
    __shared__ float c2s[NCOMM];
    __shared__ int   comms[256];
    __shared__ float x2s[256];     // holds -x^2/2
    __shared__ float sums[256], mins[256];
    __shared__ float red[8];

    int tid = threadIdx.x;
    int w  = tid >> 6;    // wave 0..3
    int l  = tid & 63;
    int lr = l & 15;      // A row within 16-frag / B (comm) col
    int lk = l >> 4;      // k-group
    int n0 = blockIdx.x * 256;

    // per-lane swizzled source offsets for staging (4 gloads per array per tile)
    int goff[4];
    #pragma unroll
    for (int i = 0; i < 4; ++i) {
        int p = i * 64 + l;
        int row = p >> 4, cp = p & 15;
        goff[i] = (row * 16 + (cp ^ row)) * 8;   // ushort index within tile
    }
    auto stage = [&](int tt, int b) {
        int base = tt * (TILE_C * DIM);
        unsigned short* lh = &Bst[w][b][0][0];
        unsigned short* ll = &Bst[w][b][1][0];
        #pragma unroll
        for (int i = 0; i < 4; ++i) {
            GLOAD_LDS16(CMh + base + goff[i], lh + i * 512);
            GLOAD_LDS16(CMl + base + goff[i], ll + i * 512);
        }
    };
    stage(0, 0);   // lands during A conversion

    c2s[tid]       = c2g[tid];
    c2s[tid + 256] = c2g[tid + 256];
    {
        int gn = n0 + tid;
        comms[tid] = (gn < N) ? comm[gn] : -1;
    }

    // ---- A fragments (rows n0 + w*64 + mf*16 + lr) + x2 (stored as -x^2/2)
    bf16x8 ah[4][4], al[4][4];
    #pragma unroll
    for (int mf = 0; mf < 4; ++mf) {
        int n = n0 + w * 64 + mf * 16 + lr;
        const float4* src = (const float4*)NF + (size_t)n * 32 + lk * 2;
        float p2 = 0.f;
        #pragma unroll
        for (int ks = 0; ks < 4; ++ks) {
            float4 v0 = make_float4(0.f, 0.f, 0.f, 0.f), v1 = v0;
            if (n < N) { v0 = src[ks * 8]; v1 = src[ks * 8 + 1]; }
            float fr[8] = {v0.x, v0.y, v0.z, v0.w, v1.x, v1.y, v1.z, v1.w};
            bf16x8 hh, ll;
            #pragma unroll
            for (int t = 0; t < 8; ++t) {
                unsigned short h = bf16_rn(fr[t]);
                hh[t] = (short)h;
                ll[t] = (short)bf16_rn(fr[t] - bf16_f(h));
                p2 = fmaf(fr[t], fr[t], p2);
            }
            ah[mf][ks] = hh; al[mf][ks] = ll;
        }
        p2 += __shfl_xor(p2, 16);
        p2 += __shfl_xor(p2, 32);
        if (lk == 0) x2s[w * 64 + mf * 16 + lr] = -0.5f * p2;
    }
    __syncthreads();   // tile0 staged (barrier drains vmcnt) + c2s/comms/x2s ready

    // per-lane per-row own-community ids (C layout: row = lk*4 + j, col = lr)
    int cnv[4][4];
    float sumv[4][4], minv[4][4];
    #pragma unroll
    for (int mf = 0; mf < 4; ++mf)
        #pragma unroll
        for (int j = 0; j < 4; ++j) {
            cnv[mf][j] = comms[w * 64 + mf * 16 + lk * 4 + j];
            sumv[mf][j] = 0.f; minv[mf][j] = BIGF;
        }

    int buf = 0;
    for (int tt = 0; tt < NT; ++tt) {
        if (tt + 1 < NT) {
            stage(tt + 1, buf ^ 1);                          // 8 loads in flight
            asm volatile("s_waitcnt vmcnt(8)" ::: "memory"); // tile tt landed
        } else {
            asm volatile("s_waitcnt vmcnt(0)" ::: "memory");
        }
        __builtin_amdgcn_sched_barrier(0);                   // fence ds_reads

        const unsigned short* bhp = &Bst[w][buf][0][0];
        const unsigned short* blp = &Bst[w][buf][1][0];
        bf16x8 bh[4], bl[4];
        #pragma unroll
        for (int ks = 0; ks < 4; ++ks) {
            int ch = (ks * 4 + lk) ^ lr;
            bh[ks] = *(const bf16x8*)&bhp[(size_t)(lr * 16 + ch) * 8];
            bl[ks] = *(const bf16x8*)&blp[(size_t)(lr * 16 + ch) * 8];
        }
        // acc init = -x^2/2 per row (one ds_read_b128 per mf)
        f32x4 acc[4];
        #pragma unroll
        for (int mf = 0; mf < 4; ++mf)
            acc[mf] = *(const f32x4*)&x2s[w * 64 + mf * 16 + lk * 4];

        #pragma unroll
        for (int ks = 0; ks < 4; ++ks) {
            #pragma unroll
            for (int mf = 0; mf < 4; ++mf)
                acc[mf] = __builtin_amdgcn_mfma_f32_16x16x32_bf16(ah[mf][ks], bh[ks], acc[mf], 0, 0, 0);
            #pragma unroll
            for (int mf = 0; mf < 4; ++mf)
                acc[mf] = __builtin_amdgcn_mfma_f32_16x16x32_bf16(al[mf][ks], bh[ks], acc[mf], 0, 0, 0);
            #pragma unroll
            for (int mf = 0; mf < 4; ++mf)
                acc[mf] = __builtin_amdgcn_mfma_f32_16x16x32_bf16(ah[mf][ks], bl[ks], acc[mf], 0, 0, 0);
        }

        int ccol = tt * TILE_C + lr;
        float c2v = c2s[ccol];
        #pragma unroll
        for (int mf = 0; mf < 4; ++mf)
            #pragma unroll
            for (int j = 0; j < 4; ++j) {
                // acc = dot - x^2/2  ->  d^2 = c^2 - 2*acc
                float d2 = fmaf(-2.f, acc[mf][j], c2v);
                float da = __builtin_amdgcn_sqrtf(fmaxf(d2, 0.f));
                sumv[mf][j] += da;
                minv[mf][j] = fminf(minv[mf][j], (cnv[mf][j] == ccol) ? BIGF : da);
            }
        buf ^= 1;
    }

    // reduce sum/min across the 16 lr lanes sharing each node row
    #pragma unroll
    for (int mf = 0; mf < 4; ++mf)
        #pragma unroll
        for (int j = 0; j < 4; ++j) {
            float sv = sumv[mf][j], mv = minv[mf][j];
            #pragma unroll
            for (int msk = 1; msk < 16; msk <<= 1) {
                sv += __shfl_xor(sv, msk);
                mv = fminf(mv, __shfl_xor(mv, msk));
            }
            if (lr == 0) {
                int idx = w * 64 + mf * 16 + lk * 4 + j;
                sums[idx] = sv; mins[idx] = mv;
            }
        }
    __syncthreads();

    // LOO positive distance + own distance + triplet terms (1 thread per node)
    float tmean = 0.f, tminv = 0.f;
    {
        int ln = tid;
        int n = n0 + ln;
        if (n < N) {
            int cnode = comms[ln];
            float cf  = countf[cnode];
            float cm1 = fmaxf(cf - 1.f, 1.f);
            float rs  = 1.f / cm1;
            bool single = (cf == 1.f);
            const float4* srow = (const float4*)(NF + (size_t)idx0[n] * DIM);
            const float4* csum = (const float4*)(comm_sum + (size_t)cnode * DIM);
            float q = 0.f, dot = 0.f;
            #pragma unroll 8
            for (int m = 0; m < 32; ++m) {
                float4 sv = srow[m];
                float4 cs = csum[m];
                float4 xm = single ? make_float4(0.f, 0.f, 0.f, 0.f) : sv;
                float lx = (cs.x - xm.x) * rs - sv.x + PEPS;
                float ly = (cs.y - xm.y) * rs - sv.y + PEPS;
                float lz = (cs.z - xm.z) * rs - sv.z + PEPS;
                float lw = (cs.w - xm.w) * rs - sv.w + PEPS;
                q = fmaf(lx, lx, fmaf(ly, ly, fmaf(lz, lz, fmaf(lw, lw, q))));
                dot = fmaf(sv.x, cs.x, fmaf(sv.y, cs.y, fmaf(sv.z, cs.z, fmaf(sv.w, cs.w, dot))));
            }
            float pos = sqrtf(q);
            float x2 = -2.f * x2s[ln];
            float ownd2 = x2 + c2s[cnode] - 2.f * (dot / cf);
            float own = sqrtf(fmaxf(ownd2, 0.f));
            float mean_neg = (sums[ln] - own) * (1.f / (float)(NCOMM - 1));
            tmean = fmaxf(pos - mean_neg + ALPHA, 0.f);
            tminv = fmaxf(pos - mins[ln] + ALPHA, 0.f);
        }
    }
    // block reduction of triplet sums
    #pragma unroll
    for (int msk = 1; msk < 64; msk <<= 1) {
        tmean += __shfl_xor(tmean, msk);
        tminv += __shfl_xor(tminv, msk);
    }
    if ((tid & 63) == 0) { red[w * 2] = tmean; red[w * 2 + 1] = tminv; }
    __syncthreads();
    if (tid == 0) {
        atomicAdd(&accum[0], red[0] + red[2] + red[4] + red[6]);
        atomicAdd(&accum[1], red[1] + red[3] + red[5] + red[7]);
    }
}

__global__ void k_final(const float* __restrict__ accum, float* __restrict__ out, int N) {
    if (threadIdx.x == 0) {
        out[0] = accum[0] / (float)N;
        out[1] = accum[1] / (float)N;
        out[2] = accum[2] / (float)(NCOMM * DIM);
    }
}

// ---------------- launch ----------------

extern "C" void kernel_launch(void* const* d_in, const int* in_sizes, int n_in,
                              void* d_out, int out_size, void* d_ws, size_t ws_size,
                              hipStream_t stream) {
    const float* NF  = (const float*)d_in[0];
    const int*   CBL = (const int*)d_in[1];
    int N = in_sizes[1] / 2;
    if (N <= 0) return;

    char* ws = (char*)d_ws;
    float* accum   = (float*)ws;                    // 16 B
    int*   counts  = (int*)(ws + 16);               // 2048
    int*   cursor  = (int*)(ws + 16 + 2048);
    int*   offsets = (int*)(ws + 16 + 2 * 2048);
    float* countf  = (float*)(ws + 16 + 3 * 2048);
    float* c2      = (float*)(ws + 16 + 4 * 2048);
    char* p = ws + 16 + 5 * 2048;
    int* inv    = (int*)p; p += (size_t)N * 4;
    int* comm   = (int*)p; p += (size_t)N * 4;
    int* idx0   = (int*)p; p += (size_t)N * 4;
    int* sorted = (int*)p; p += (size_t)N * 4;
    float* comm_sum = (float*)p; p += (size_t)NCOMM * DIM * 4;
    unsigned short* CMh = (unsigned short*)p; p += (size_t)NCOMM * DIM * 2;
    unsigned short* CMl = (unsigned short*)p;

    hipMemsetAsync(d_ws, 0, 16 + 2048, stream);     // accum + counts

    int nb = (N + 255) / 256;
    k_inv <<<nb, 256, 0, stream>>>(CBL, inv, N);
    k_comm<<<nb, 256, 0, stream>>>(CBL, inv, comm, idx0, counts, N);
    k_scan<<<1, NCOMM, 0, stream>>>(counts, offsets, cursor, countf);
    int nb4 = (N + 1023) / 1024;
    k_sort<<<nb4, 256, 0, stream>>>(comm, cursor, sorted, N);
    k_stats<<<NCOMM, 256, 0, stream>>>(NF, idx0, sorted, offsets, counts,
                                       comm_sum, CMh, CMl, c2, accum);
    int mb = (N + 255) / 256;
    k_main<<<mb, 256, 0, stream>>>(NF, CMh, CMl, comm_sum, c2, countf,
                                   comm, idx0, accum, N);
    k_final<<<1, 64, 0, stream>>>(accum, (float*)d_out, N);
}

// Round 7
// 129.872 us; speedup vs baseline: 1.7229x; 1.1429x over previous
//
#include <hip/hip_runtime.h>

#define NCOMM 512
#define DIM   128
#define ALPHA 0.25f
#define PEPS  1e-6f
#define BIGF  1e30f
#define TILE_C 16
#define NT    (NCOMM / TILE_C)   // 32 tiles

typedef __attribute__((ext_vector_type(8))) _Float16 f16x8;
typedef __attribute__((ext_vector_type(4))) float f32x4;

#define GLOAD_LDS16(g, l) __builtin_amdgcn_global_load_lds( \
    (const __attribute__((address_space(1))) void*)(g), \
    (__attribute__((address_space(3))) void*)(l), 16, 0, 0)

// ---------------- small prep kernels ----------------

__global__ void k_inv(const int* __restrict__ cbl, int* __restrict__ inv, int N) {
    int i = blockIdx.x * 256 + threadIdx.x;
    if (i < N) inv[cbl[i]] = i;   // perm is a permutation: direct store == scatter-add on zeros
}

__global__ void k_comm(const int* __restrict__ cbl, const int* __restrict__ inv,
                       int* __restrict__ comm, int* __restrict__ idx0,
                       int* __restrict__ counts, int N) {
    __shared__ int h[NCOMM];
    int t = threadIdx.x;
    h[t] = 0; h[t + 256] = 0;
    __syncthreads();
    int j = blockIdx.x * 256 + t;
    if (j < N) {
        int ij = inv[j];
        int c  = cbl[N + ij];
        comm[j] = c;
        idx0[j] = cbl[ij];
        atomicAdd(&h[c], 1);
    }
    __syncthreads();
    int v = h[t];        if (v) atomicAdd(&counts[t], v);
    v = h[t + 256];      if (v) atomicAdd(&counts[t + 256], v);
}

__global__ void k_scan(const int* __restrict__ counts, int* __restrict__ offsets,
                       int* __restrict__ cursor, float* __restrict__ countf) {
    __shared__ int sc[NCOMM];
    int t = threadIdx.x;
    int v0 = counts[t];
    sc[t] = v0;
    __syncthreads();
    for (int off = 1; off < NCOMM; off <<= 1) {
        int v = (t >= off) ? sc[t - off] : 0;
        __syncthreads();
        sc[t] += v;
        __syncthreads();
    }
    int excl = sc[t] - v0;
    offsets[t] = excl;
    cursor[t]  = excl;
    countf[t]  = (float)v0;
}

// 1024 elements per block: LDS histogram + one range-reservation atomic per present comm
__global__ void k_sort(const int* __restrict__ comm, int* __restrict__ cursor,
                       int* __restrict__ sorted, int N) {
    __shared__ int h[NCOMM], hb[NCOMM];
    int t = threadIdx.x;
    h[t] = 0; h[t + 256] = 0;
    __syncthreads();
    int j0 = blockIdx.x * 1024 + t;
    int cs[4];
    #pragma unroll
    for (int q = 0; q < 4; ++q) {
        int j = j0 + q * 256;
        cs[q] = (j < N) ? comm[j] : -1;
        if (cs[q] >= 0) atomicAdd(&h[cs[q]], 1);
    }
    __syncthreads();
    int v = h[t];        if (v) hb[t] = atomicAdd(&cursor[t], v);
    v = h[t + 256];      if (v) hb[t + 256] = atomicAdd(&cursor[t + 256], v);
    __syncthreads();
    #pragma unroll
    for (int q = 0; q < 4; ++q) {
        int j = j0 + q * 256;
        if (cs[q] >= 0) {
            int p = atomicAdd(&hb[cs[q]], 1);
            sorted[p] = j;
        }
    }
}

// ---------------- per-community stats: float4 gather, single pass ----------------
// var = (sumsq - cnt*m^2)/(cnt-1): benign cancellation (x~N(0,1), rel err ~1e-6)
// Emits community means as fp16 hi/lo split (22-bit mantissa ~= fp32).

__global__ void __launch_bounds__(256) k_stats(
        const float* __restrict__ NF, const int* __restrict__ idx0,
        const int* __restrict__ sorted, const int* __restrict__ offsets,
        const int* __restrict__ counts,
        float* __restrict__ comm_sum,
        _Float16* __restrict__ CMh, _Float16* __restrict__ CMl,
        float* __restrict__ c2, float* __restrict__ accum) {
    __shared__ int ridx[512];
    __shared__ float4 bufS[256], bufQ[256];
    int c = blockIdx.x, t = threadIdx.x;
    int d4 = t & 31, r = t >> 5;                 // 32 dim-quads x 8 row slots
    int cnt = counts[c], base = offsets[c];
    const float4* NF4 = (const float4*)NF;

    float4 s4 = make_float4(0.f, 0.f, 0.f, 0.f);
    float4 q4 = make_float4(0.f, 0.f, 0.f, 0.f);
    for (int chunk = 0; chunk < cnt; chunk += 512) {
        int m = min(cnt - chunk, 512);
        for (int i = t; i < m; i += 256) ridx[i] = idx0[sorted[base + chunk + i]];
        __syncthreads();
        for (int i = r; i < m; i += 8) {
            float4 v = NF4[(size_t)ridx[i] * 32 + d4];
            s4.x += v.x; s4.y += v.y; s4.z += v.z; s4.w += v.w;
            q4.x = fmaf(v.x, v.x, q4.x); q4.y = fmaf(v.y, v.y, q4.y);
            q4.z = fmaf(v.z, v.z, q4.z); q4.w = fmaf(v.w, v.w, q4.w);
        }
        __syncthreads();
    }
    bufS[t] = s4; bufQ[t] = q4;
    __syncthreads();
    if (t < 128) {
        float4 a = bufS[t], b = bufS[t + 128];
        a.x += b.x; a.y += b.y; a.z += b.z; a.w += b.w; bufS[t] = a;
        float4 e = bufQ[t], f = bufQ[t + 128];
        e.x += f.x; e.y += f.y; e.z += f.z; e.w += f.w; bufQ[t] = e;
    }
    __syncthreads();
    if (t < 64) {
        float4 a = bufS[t], b = bufS[t + 64];
        a.x += b.x; a.y += b.y; a.z += b.z; a.w += b.w; bufS[t] = a;
        float4 e = bufQ[t], f = bufQ[t + 64];
        e.x += f.x; e.y += f.y; e.z += f.z; e.w += f.w; bufQ[t] = e;
    }
    __syncthreads();
    if (t < 32) {
        float4 a = bufS[t], b = bufS[t + 32];
        a.x += b.x; a.y += b.y; a.z += b.z; a.w += b.w;
        float4 e = bufQ[t], f = bufQ[t + 32];
        e.x += f.x; e.y += f.y; e.z += f.z; e.w += f.w;
        float sarr[4] = {a.x, a.y, a.z, a.w};
        float qarr[4] = {e.x, e.y, e.z, e.w};
        float cf = (float)cnt;
        float mm = 0.f, ee = 0.f;
        #pragma unroll
        for (int k = 0; k < 4; ++k) {
            int d = t * 4 + k;
            float s = sarr[k];
            comm_sum[c * DIM + d] = s;
            float m = (cnt > 0) ? s / cf : 0.f;
            _Float16 mh = (_Float16)m;
            CMh[c * DIM + d] = mh;
            CMl[c * DIM + d] = (_Float16)(m - (float)mh);
            float varn = fmaxf(fmaf(-cf * m, m, qarr[k]), 0.f);
            float stdv = sqrtf(varn / fmaxf(cf - 1.f, 1.f));
            float er = stdv - 1.f;
            mm = fmaf(m, m, mm);
            ee = fmaf(er, er, ee);
        }
        #pragma unroll
        for (int msk = 1; msk < 32; msk <<= 1) {
            mm += __shfl_xor(mm, msk);
            ee += __shfl_xor(ee, msk);
        }
        if (t == 0) {
            c2[c] = mm;
            atomicAdd(&accum[2], ee);
        }
    }
}

// ---------------- heavy kernel: MFMA distances + triplet terms ----------------
// 256 threads (4 waves x 64 rows = 256 nodes/block). ASYMMETRIC fp16 precision:
// A = single fp16 (64 VGPR for M=64 -- fits without spill), B = fp16 hi/lo
// (22-bit, ~fp32). dot err ~2e-4 in d^2 -> ~1e-5 in outputs. 2 MFMAs per
// ks (a*bh + a*bl) = 32 MFMA/tile. Wave-private dbuf LDS staging, counted
// s_waitcnt vmcnt(8), no K-loop barrier. acc C-init = -x^2/2 from LDS.

__global__ void __launch_bounds__(256, 2) k_main(
        const float* __restrict__ NF,
        const _Float16* __restrict__ CMh,
        const _Float16* __restrict__ CMl,
        const float* __restrict__ comm_sum,
        const float* __restrict__ c2g,
        const float* __restrict__ countf,
        const int* __restrict__ comm,
        const int* __restrict__ idx0,
        float* __restrict__ accum, int N) {
    __shared__ _Float16 Bst[4][2][2][TILE_C * DIM];  // [wave][buf][h/l] = 64 KB
    __shared__ float c2s[NCOMM];
    __shared__ int   comms[256];
    __shared__ float x2s[256];     // holds -x^2/2
    __shared__ float sums[256], mins[256];
    __shared__ float red[8];

    int tid = threadIdx.x;
    int w  = tid >> 6;    // wave 0..3
    int l  = tid & 63;
    int lr = l & 15;      // A row within 16-frag / B (comm) col
    int lk = l >> 4;      // k-group
    int n0 = blockIdx.x * 256;

    // per-lane swizzled source offsets for staging (4 gloads per array per tile)
    int goff[4];
    #pragma unroll
    for (int i = 0; i < 4; ++i) {
        int p = i * 64 + l;
        int row = p >> 4, cp = p & 15;
        goff[i] = (row * 16 + (cp ^ row)) * 8;   // fp16 index within tile
    }
    auto stage = [&](int tt, int b) {
        int base = tt * (TILE_C * DIM);
        _Float16* lh = &Bst[w][b][0][0];
        _Float16* ll = &Bst[w][b][1][0];
        #pragma unroll
        for (int i = 0; i < 4; ++i) {
            GLOAD_LDS16(CMh + base + goff[i], lh + i * 512);
            GLOAD_LDS16(CMl + base + goff[i], ll + i * 512);
        }
    };
    stage(0, 0);   // lands during A conversion

    c2s[tid]       = c2g[tid];
    c2s[tid + 256] = c2g[tid + 256];
    {
        int gn = n0 + tid;
        comms[tid] = (gn < N) ? comm[gn] : -1;
    }

    // ---- A fragments (rows n0 + w*64 + mf*16 + lr), single fp16 + exact fp32 x2
    f16x8 ah[4][4];
    #pragma unroll
    for (int mf = 0; mf < 4; ++mf) {
        int n = n0 + w * 64 + mf * 16 + lr;
        const float4* src = (const float4*)NF + (size_t)n * 32 + lk * 2;
        float p2 = 0.f;
        #pragma unroll
        for (int ks = 0; ks < 4; ++ks) {
            float4 v0 = make_float4(0.f, 0.f, 0.f, 0.f), v1 = v0;
            if (n < N) { v0 = src[ks * 8]; v1 = src[ks * 8 + 1]; }
            float fr[8] = {v0.x, v0.y, v0.z, v0.w, v1.x, v1.y, v1.z, v1.w};
            f16x8 hh;
            #pragma unroll
            for (int t = 0; t < 8; ++t) {
                hh[t] = (_Float16)fr[t];
                p2 = fmaf(fr[t], fr[t], p2);
            }
            ah[mf][ks] = hh;
        }
        p2 += __shfl_xor(p2, 16);
        p2 += __shfl_xor(p2, 32);
        if (lk == 0) x2s[w * 64 + mf * 16 + lr] = -0.5f * p2;
    }
    __syncthreads();   // tile0 staged (barrier drains vmcnt) + c2s/comms/x2s ready

    // per-lane per-row own-community ids (C layout: row = lk*4 + j, col = lr)
    int cnv[4][4];
    float sumv[4][4], minv[4][4];
    #pragma unroll
    for (int mf = 0; mf < 4; ++mf)
        #pragma unroll
        for (int j = 0; j < 4; ++j) {
            cnv[mf][j] = comms[w * 64 + mf * 16 + lk * 4 + j];
            sumv[mf][j] = 0.f; minv[mf][j] = BIGF;
        }

    int buf = 0;
    for (int tt = 0; tt < NT; ++tt) {
        if (tt + 1 < NT) {
            stage(tt + 1, buf ^ 1);                          // 8 loads in flight
            asm volatile("s_waitcnt vmcnt(8)" ::: "memory"); // tile tt landed
        } else {
            asm volatile("s_waitcnt vmcnt(0)" ::: "memory");
        }
        __builtin_amdgcn_sched_barrier(0);                   // fence ds_reads

        const _Float16* bhp = &Bst[w][buf][0][0];
        const _Float16* blp = &Bst[w][buf][1][0];
        f16x8 bh[4], bl[4];
        #pragma unroll
        for (int ks = 0; ks < 4; ++ks) {
            int ch = (ks * 4 + lk) ^ lr;
            bh[ks] = *(const f16x8*)&bhp[(size_t)(lr * 16 + ch) * 8];
            bl[ks] = *(const f16x8*)&blp[(size_t)(lr * 16 + ch) * 8];
        }
        // acc init = -x^2/2 per row (one ds_read_b128 per mf)
        f32x4 acc[4];
        #pragma unroll
        for (int mf = 0; mf < 4; ++mf)
            acc[mf] = *(const f32x4*)&x2s[w * 64 + mf * 16 + lk * 4];

        #pragma unroll
        for (int ks = 0; ks < 4; ++ks) {
            #pragma unroll
            for (int mf = 0; mf < 4; ++mf)
                acc[mf] = __builtin_amdgcn_mfma_f32_16x16x32_f16(ah[mf][ks], bh[ks], acc[mf], 0, 0, 0);
            #pragma unroll
            for (int mf = 0; mf < 4; ++mf)
                acc[mf] = __builtin_amdgcn_mfma_f32_16x16x32_f16(ah[mf][ks], bl[ks], acc[mf], 0, 0, 0);
        }

        int ccol = tt * TILE_C + lr;
        float c2v = c2s[ccol];
        #pragma unroll
        for (int mf = 0; mf < 4; ++mf)
            #pragma unroll
            for (int j = 0; j < 4; ++j) {
                // acc = dot - x^2/2  ->  d^2 = c^2 - 2*acc
                float d2 = fmaf(-2.f, acc[mf][j], c2v);
                float da = __builtin_amdgcn_sqrtf(fmaxf(d2, 0.f));
                sumv[mf][j] += da;
                minv[mf][j] = fminf(minv[mf][j], (cnv[mf][j] == ccol) ? BIGF : da);
            }
        buf ^= 1;
    }

    // reduce sum/min across the 16 lr lanes sharing each node row
    #pragma unroll
    for (int mf = 0; mf < 4; ++mf)
        #pragma unroll
        for (int j = 0; j < 4; ++j) {
            float sv = sumv[mf][j], mv = minv[mf][j];
            #pragma unroll
            for (int msk = 1; msk < 16; msk <<= 1) {
                sv += __shfl_xor(sv, msk);
                mv = fminf(mv, __shfl_xor(mv, msk));
            }
            if (lr == 0) {
                int idx = w * 64 + mf * 16 + lk * 4 + j;
                sums[idx] = sv; mins[idx] = mv;
            }
        }
    __syncthreads();

    // LOO positive distance + own distance + triplet terms (1 thread per node)
    float tmean = 0.f, tminv = 0.f;
    {
        int ln = tid;
        int n = n0 + ln;
        if (n < N) {
            int cnode = comms[ln];
            float cf  = countf[cnode];
            float cm1 = fmaxf(cf - 1.f, 1.f);
            float rs  = 1.f / cm1;
            bool single = (cf == 1.f);
            const float4* srow = (const float4*)(NF + (size_t)idx0[n] * DIM);
            const float4* csum = (const float4*)(comm_sum + (size_t)cnode * DIM);
            float q = 0.f, dot = 0.f;
            #pragma unroll 8
            for (int m = 0; m < 32; ++m) {
                float4 sv = srow[m];
                float4 cs = csum[m];
                float4 xm = single ? make_float4(0.f, 0.f, 0.f, 0.f) : sv;
                float lx = (cs.x - xm.x) * rs - sv.x + PEPS;
                float ly = (cs.y - xm.y) * rs - sv.y + PEPS;
                float lz = (cs.z - xm.z) * rs - sv.z + PEPS;
                float lw = (cs.w - xm.w) * rs - sv.w + PEPS;
                q = fmaf(lx, lx, fmaf(ly, ly, fmaf(lz, lz, fmaf(lw, lw, q))));
                dot = fmaf(sv.x, cs.x, fmaf(sv.y, cs.y, fmaf(sv.z, cs.z, fmaf(sv.w, cs.w, dot))));
            }
            float pos = sqrtf(q);
            float x2 = -2.f * x2s[ln];
            float ownd2 = x2 + c2s[cnode] - 2.f * (dot / cf);
            float own = sqrtf(fmaxf(ownd2, 0.f));
            float mean_neg = (sums[ln] - own) * (1.f / (float)(NCOMM - 1));
            tmean = fmaxf(pos - mean_neg + ALPHA, 0.f);
            tminv = fmaxf(pos - mins[ln] + ALPHA, 0.f);
        }
    }
    // block reduction of triplet sums
    #pragma unroll
    for (int msk = 1; msk < 64; msk <<= 1) {
        tmean += __shfl_xor(tmean, msk);
        tminv += __shfl_xor(tminv, msk);
    }
    if ((tid & 63) == 0) { red[w * 2] = tmean; red[w * 2 + 1] = tminv; }
    __syncthreads();
    if (tid == 0) {
        atomicAdd(&accum[0], red[0] + red[2] + red[4] + red[6]);
        atomicAdd(&accum[1], red[1] + red[3] + red[5] + red[7]);
    }
}

__global__ void k_final(const float* __restrict__ accum, float* __restrict__ out, int N) {
    if (threadIdx.x == 0) {
        out[0] = accum[0] / (float)N;
        out[1] = accum[1] / (float)N;
        out[2] = accum[2] / (float)(NCOMM * DIM);
    }
}

// ---------------- launch ----------------

extern "C" void kernel_launch(void* const* d_in, const int* in_sizes, int n_in,
                              void* d_out, int out_size, void* d_ws, size_t ws_size,
                              hipStream_t stream) {
    const float* NF  = (const float*)d_in[0];
    const int*   CBL = (const int*)d_in[1];
    int N = in_sizes[1] / 2;
    if (N <= 0) return;

    char* ws = (char*)d_ws;
    float* accum   = (float*)ws;                    // 16 B
    int*   counts  = (int*)(ws + 16);               // 2048
    int*   cursor  = (int*)(ws + 16 + 2048);
    int*   offsets = (int*)(ws + 16 + 2 * 2048);
    float* countf  = (float*)(ws + 16 + 3 * 2048);
    float* c2      = (float*)(ws + 16 + 4 * 2048);
    char* p = ws + 16 + 5 * 2048;
    int* inv    = (int*)p; p += (size_t)N * 4;
    int* comm   = (int*)p; p += (size_t)N * 4;
    int* idx0   = (int*)p; p += (size_t)N * 4;
    int* sorted = (int*)p; p += (size_t)N * 4;
    float* comm_sum = (float*)p; p += (size_t)NCOMM * DIM * 4;
    _Float16* CMh = (_Float16*)p; p += (size_t)NCOMM * DIM * 2;
    _Float16* CMl = (_Float16*)p;

    hipMemsetAsync(d_ws, 0, 16 + 2048, stream);     // accum + counts

    int nb = (N + 255) / 256;
    k_inv <<<nb, 256, 0, stream>>>(CBL, inv, N);
    k_comm<<<nb, 256, 0, stream>>>(CBL, inv, comm, idx0, counts, N);
    k_scan<<<1, NCOMM, 0, stream>>>(counts, offsets, cursor, countf);
    int nb4 = (N + 1023) / 1024;
    k_sort<<<nb4, 256, 0, stream>>>(comm, cursor, sorted, N);
    k_stats<<<NCOMM, 256, 0, stream>>>(NF, idx0, sorted, offsets, counts,
                                       comm_sum, CMh, CMl, c2, accum);
    int mb = (N + 255) / 256;
    k_main<<<mb, 256, 0, stream>>>(NF, CMh, CMl, comm_sum, c2, countf,
                                   comm, idx0, accum, N);
    k_final<<<1, 64, 0, stream>>>(accum, (float*)d_out, N);
}